// Round 6
// baseline (656.404 us; speedup 1.0000x reference)
//
#include <hip/hip_runtime.h>
#include <hip/hip_bf16.h>
#include <stdint.h>
#include <stddef.h>

using bf16 = __hip_bfloat16;
using frag_ab = __attribute__((ext_vector_type(8))) short;  // 8 bf16 (4 VGPRs)
using frag_cd = __attribute__((ext_vector_type(4))) float;  // 4 fp32 acc

constexpr int BM = 128, BN = 128, BK = 32;

// async global->LDS DMA, 16 B/lane; LDS dest = wave-uniform base + lane*16
#define GLOAD_LDS16(gp, lp)                                        \
    __builtin_amdgcn_global_load_lds(                              \
        (const __attribute__((address_space(1))) unsigned int*)(gp),\
        (__attribute__((address_space(3))) unsigned int*)(lp), 16, 0, 0)

// capture-safe zero fill (float4 stores), grid-stride
__global__ __launch_bounds__(256) void zero_f32(float* __restrict__ p, size_t nelem)
{
    const size_t stride = (size_t)gridDim.x * 256 * 4;
    for (size_t i = ((size_t)blockIdx.x * 256 + threadIdx.x) * 4; i < nelem; i += stride) {
        float4 z = {0.f, 0.f, 0.f, 0.f};
        *reinterpret_cast<float4*>(p + i) = z;
    }
}

// ---------------------------------------------------------------------------
// Split-precision GEMM: C = (Ahi+Alo) @ (Bhi+Blo)^T dropping the lo*lo term.
// 48 MFMA per barrier pair (4 tiles staged at once, 32 KB LDS).
// EPI: 1 = split bf16 hi/lo store, 2 = fp32 atomicAdd (for split-K partials).
// CAUSAL: skip blocks with bx > by. SPLITK: blockIdx.z picks K-half.
template <int EPI, bool CAUSAL, bool SPLITK>
__global__ __launch_bounds__(256) void gemm_bt_split3(
    const bf16* __restrict__ Ahi, const bf16* __restrict__ Alo,
    const bf16* __restrict__ Bhi, const bf16* __restrict__ Blo,
    float* __restrict__ Cf, bf16* __restrict__ Co, bf16* __restrict__ Clo,
    int M, int N, int K)
{
    const int bx = blockIdx.x;  // N tile
    const int by = blockIdx.y;  // M tile
    if (CAUSAL && bx > by) return;

    const int tid   = threadIdx.x;
    const int lane  = tid & 63;
    const int wave  = tid >> 6;
    const int wm    = wave >> 1;
    const int wn    = wave & 1;
    const int lrow  = lane & 15;
    const int lquad = lane >> 4;

    __shared__ bf16 sAh[BM * BK];  // 8 KB each, 32 KB total
    __shared__ bf16 sAl[BM * BK];
    __shared__ bf16 sBh[BN * BK];
    __shared__ bf16 sBl[BN * BK];

    const int row0 = by * BM;
    const int col0 = bx * BN;

    const int srow = tid >> 2;
    const int scol = (tid & 3) * 8;
    const int lbase = wave * 512;  // wave-uniform LDS element base (+r*2048)

    frag_cd acc[4][4];
    const frag_cd fzero = {0.f, 0.f, 0.f, 0.f};
    #pragma unroll
    for (int i = 0; i < 4; ++i)
        #pragma unroll
        for (int j = 0; j < 4; ++j) acc[i][j] = fzero;

    const int Klen = SPLITK ? (K >> 1) : K;
    const int kbeg = SPLITK ? blockIdx.z * Klen : 0;

    for (int k0 = kbeg; k0 < kbeg + Klen; k0 += BK) {
        __syncthreads();
        #pragma unroll
        for (int r = 0; r < 2; ++r) {
            const int trow = srow + 64 * r;
            const size_t ga = (size_t)(row0 + trow) * K + k0 + scol;
            const size_t gb = (size_t)(col0 + trow) * K + k0 + scol;
            const int ldst = lbase + r * 2048;
            GLOAD_LDS16(&Ahi[ga], &sAh[ldst]);
            GLOAD_LDS16(&Alo[ga], &sAl[ldst]);
            GLOAD_LDS16(&Bhi[gb], &sBh[ldst]);
            GLOAD_LDS16(&Blo[gb], &sBl[ldst]);
        }
        __syncthreads();

        frag_ab ah[4], al[4], bh[4], bl[4];
        #pragma unroll
        for (int mi = 0; mi < 4; ++mi) {
            const int off = (wm * 64 + mi * 16 + lrow) * BK + lquad * 8;
            ah[mi] = *reinterpret_cast<const frag_ab*>(&sAh[off]);
            al[mi] = *reinterpret_cast<const frag_ab*>(&sAl[off]);
        }
        #pragma unroll
        for (int ni = 0; ni < 4; ++ni) {
            const int off = (wn * 64 + ni * 16 + lrow) * BK + lquad * 8;
            bh[ni] = *reinterpret_cast<const frag_ab*>(&sBh[off]);
            bl[ni] = *reinterpret_cast<const frag_ab*>(&sBl[off]);
        }

        #pragma unroll
        for (int mi = 0; mi < 4; ++mi)
            #pragma unroll
            for (int ni = 0; ni < 4; ++ni) {
                acc[mi][ni] = __builtin_amdgcn_mfma_f32_16x16x32_bf16(
                    ah[mi], bh[ni], acc[mi][ni], 0, 0, 0);
                acc[mi][ni] = __builtin_amdgcn_mfma_f32_16x16x32_bf16(
                    al[mi], bh[ni], acc[mi][ni], 0, 0, 0);
                acc[mi][ni] = __builtin_amdgcn_mfma_f32_16x16x32_bf16(
                    ah[mi], bl[ni], acc[mi][ni], 0, 0, 0);
            }
    }

    #pragma unroll
    for (int mi = 0; mi < 4; ++mi) {
        #pragma unroll
        for (int ni = 0; ni < 4; ++ni) {
            #pragma unroll
            for (int r = 0; r < 4; ++r) {
                const int row = row0 + wm * 64 + mi * 16 + lquad * 4 + r;
                const int col = col0 + wn * 64 + ni * 16 + lrow;
                const size_t idx = (size_t)row * N + col;
                const float v = acc[mi][ni][r];
                if (EPI == 1) {
                    const bf16 h = (bf16)v;
                    Co[idx]  = h;
                    Clo[idx] = (bf16)(v - (float)h);
                } else {
                    atomicAdd(&Cf[idx], v);
                }
            }
        }
    }
}

// ---------------------------------------------------------------------------
// Plain GEMM: C = A @ B^T (bf16 in).
// EPI: 0 = fp32 store, 2 = bf16 store, 3 = fp32 atomicAdd (split-K).
// KCAUSAL: K limited to (by+1)*BM; by reversed so heavy blocks dispatch first.
template <int EPI, bool KCAUSAL, bool SPLITK>
__global__ __launch_bounds__(256) void gemm_bt(
    const bf16* __restrict__ A, const bf16* __restrict__ B,
    float* __restrict__ Cf, bf16* __restrict__ Co,
    int M, int N, int K)
{
    const int bx = blockIdx.x;
    const int by = KCAUSAL ? (gridDim.y - 1 - blockIdx.y) : blockIdx.y;

    const int tid   = threadIdx.x;
    const int lane  = tid & 63;
    const int wave  = tid >> 6;
    const int wm    = wave >> 1;
    const int wn    = wave & 1;
    const int lrow  = lane & 15;
    const int lquad = lane >> 4;

    __shared__ bf16 sA[BM * BK];
    __shared__ bf16 sB[BN * BK];

    const int row0 = by * BM;
    const int col0 = bx * BN;

    const int srow = tid >> 2;
    const int scol = (tid & 3) * 8;
    const int lbase = wave * 512;

    frag_cd acc[4][4];
    const frag_cd fzero = {0.f, 0.f, 0.f, 0.f};
    #pragma unroll
    for (int i = 0; i < 4; ++i)
        #pragma unroll
        for (int j = 0; j < 4; ++j) acc[i][j] = fzero;

    const int Keff = KCAUSAL ? (by + 1) * BM : K;
    const int Klen = SPLITK ? (Keff >> 1) : Keff;
    const int kbeg = SPLITK ? blockIdx.z * Klen : 0;

    for (int k0 = kbeg; k0 < kbeg + Klen; k0 += BK) {
        __syncthreads();
        #pragma unroll
        for (int r = 0; r < 2; ++r) {
            const int trow = srow + 64 * r;
            GLOAD_LDS16(&A[(size_t)(row0 + trow) * K + k0 + scol], &sA[lbase + r * 2048]);
            GLOAD_LDS16(&B[(size_t)(col0 + trow) * K + k0 + scol], &sB[lbase + r * 2048]);
        }
        __syncthreads();

        frag_ab av[4], bv[4];
        #pragma unroll
        for (int mi = 0; mi < 4; ++mi)
            av[mi] = *reinterpret_cast<const frag_ab*>(
                &sA[(wm * 64 + mi * 16 + lrow) * BK + lquad * 8]);
        #pragma unroll
        for (int ni = 0; ni < 4; ++ni)
            bv[ni] = *reinterpret_cast<const frag_ab*>(
                &sB[(wn * 64 + ni * 16 + lrow) * BK + lquad * 8]);

        #pragma unroll
        for (int mi = 0; mi < 4; ++mi)
            #pragma unroll
            for (int ni = 0; ni < 4; ++ni)
                acc[mi][ni] = __builtin_amdgcn_mfma_f32_16x16x32_bf16(
                    av[mi], bv[ni], acc[mi][ni], 0, 0, 0);
    }

    #pragma unroll
    for (int mi = 0; mi < 4; ++mi) {
        #pragma unroll
        for (int ni = 0; ni < 4; ++ni) {
            #pragma unroll
            for (int r = 0; r < 4; ++r) {
                const int row = row0 + wm * 64 + mi * 16 + lquad * 4 + r;
                const int col = col0 + wn * 64 + ni * 16 + lrow;
                const size_t idx = (size_t)row * N + col;
                const float v = acc[mi][ni][r];
                if (EPI == 0)      Cf[idx] = v;
                else if (EPI == 2) Co[idx] = (bf16)v;
                else               atomicAdd(&Cf[idx], v);
            }
        }
    }
}

// fp32 -> bf16 hi (+ optional lo residual), 4 elems/thread
__global__ __launch_bounds__(256) void split_fp32(
    const float* __restrict__ in, bf16* __restrict__ hi, bf16* __restrict__ lo,
    size_t nelem)
{
    const size_t i = ((size_t)blockIdx.x * 256 + threadIdx.x) * 4;
    if (i >= nelem) return;
    const float4 v = *reinterpret_cast<const float4*>(in + i);
    union { bf16 b[4]; ushort4 u; } H, L;
    H.b[0] = (bf16)v.x; H.b[1] = (bf16)v.y; H.b[2] = (bf16)v.z; H.b[3] = (bf16)v.w;
    *reinterpret_cast<ushort4*>(hi + i) = H.u;
    if (lo) {
        L.b[0] = (bf16)(v.x - (float)H.b[0]);
        L.b[1] = (bf16)(v.y - (float)H.b[1]);
        L.b[2] = (bf16)(v.z - (float)H.b[2]);
        L.b[3] = (bf16)(v.w - (float)H.b[3]);
        *reinterpret_cast<ushort4*>(lo + i) = L.u;
    }
}

// row-wise causal softmax, online max+sum; zero-pads P to the 128 boundary.
__global__ __launch_bounds__(256) void softmax_rows(
    const float* __restrict__ S, bf16* __restrict__ P, int n)
{
    const int row = blockIdx.x;
    const int len = row + 1;
    const int padlen = ((row >> 7) + 1) << 7;
    const float* srow = S + (size_t)row * n;
    bf16* prow = P + (size_t)row * n;
    const int tid = threadIdx.x;
    const int lane = tid & 63, wave = tid >> 6;
    __shared__ float redm[4], reds[4];

    float m = -3.0e38f, s = 0.f;
    for (int j = tid; j < len; j += 256) {
        const float v = srow[j];
        const float mn = fmaxf(m, v);
        s = s * __expf(m - mn) + __expf(v - mn);
        m = mn;
    }
    #pragma unroll
    for (int off = 32; off; off >>= 1) {
        const float mo = __shfl_xor(m, off, 64);
        const float so = __shfl_xor(s, off, 64);
        const float mn = fmaxf(m, mo);
        s = s * __expf(m - mn) + so * __expf(mo - mn);
        m = mn;
    }
    if (lane == 0) { redm[wave] = m; reds[wave] = s; }
    __syncthreads();
    float M = redm[0], Sm = reds[0];
    #pragma unroll
    for (int w = 1; w < 4; ++w) {
        const float mn = fmaxf(M, redm[w]);
        Sm = Sm * __expf(M - mn) + reds[w] * __expf(redm[w] - mn);
        M = mn;
    }
    const float inv = 1.0f / Sm;

    const bf16 z = (bf16)0.0f;
    for (int j = tid; j < padlen; j += 256)
        prow[j] = (j < len) ? (bf16)(__expf(srow[j] - M) * inv) : z;
}

// out[c*rows + r] = (bf16)in[r*cols + c]   (fp32 in, bf16 out)
__global__ __launch_bounds__(256) void transpose_f32_bf16(
    const float* __restrict__ in, bf16* __restrict__ out, int rows, int cols)
{
    __shared__ float tile[32][33];
    const int bx = blockIdx.x;
    const int by = blockIdx.y;
    const int tx = threadIdx.x & 31;
    const int ty = threadIdx.x >> 5;
    #pragma unroll
    for (int r = 0; r < 4; ++r)
        tile[ty + 8 * r][tx] = in[(size_t)(by * 32 + ty + 8 * r) * cols + bx * 32 + tx];
    __syncthreads();
    #pragma unroll
    for (int r = 0; r < 4; ++r)
        out[(size_t)(bx * 32 + ty + 8 * r) * rows + by * 32 + tx] =
            (bf16)tile[tx][ty + 8 * r];
}

extern "C" void kernel_launch(void* const* d_in, const int* in_sizes, int n_in,
                              void* d_out, int out_size, void* d_ws, size_t ws_size,
                              hipStream_t stream)
{
    const int n = 4096, d = 2048;
    const float* x   = (const float*)d_in[0];
    const float* Wqk = (const float*)d_in[1];
    const float* Wov = (const float*)d_in[2];
    float* out = (float*)d_out;

    char* ws = (char*)d_ws;
    const size_t MB = 1 << 20;
    bf16*  xhi  = (bf16*)(ws);              // 16 MB  (n x d)
    bf16*  xlo  = (bf16*)(ws + 16  * MB);   // 16 MB
    bf16*  Whi  = (bf16*)(ws + 32  * MB);   //  8 MB  (d x d)
    bf16*  Wlo  = (bf16*)(ws + 40  * MB);   //  8 MB
    bf16*  Wov_h= (bf16*)(ws + 48  * MB);   //  8 MB
    bf16*  xT   = (bf16*)(ws + 56  * MB);   // 16 MB  (d x n)
    bf16*  qhi  = (bf16*)(ws + 72  * MB);   // 16 MB  (n x d)
    bf16*  qlo  = (bf16*)(ws + 88  * MB);   // 16 MB
    float* q32  = (float*)(ws + 104 * MB);  // 32 MB  (n x d), lives in S region
    float* S    = (float*)(ws + 104 * MB);  // 64 MB  (n x n)  -> peak 168 MB
    bf16*  P    = (bf16*)(ws);              // 32 MB  (n x n), reuses xhi+xlo (dead)
    bf16*  o    = (bf16*)(ws + 32  * MB);   // 16 MB  (n x d), reuses Whi+Wlo (dead)

    const dim3 blk(256);

    // zero split-K accumulation target for out (kernel, capture-safe)
    zero_f32<<<dim3(2048), blk, 0, stream>>>(out, (size_t)n * d);

    // input fp32 -> bf16 hi/lo
    split_fp32<<<dim3((n * d) / (256 * 4)), blk, 0, stream>>>(x,   xhi, xlo, (size_t)n * d);
    split_fp32<<<dim3((d * d) / (256 * 4)), blk, 0, stream>>>(Wqk, Whi, Wlo, (size_t)d * d);
    split_fp32<<<dim3((d * d) / (256 * 4)), blk, 0, stream>>>(Wov, Wov_h, nullptr, (size_t)d * d);
    transpose_f32_bf16<<<dim3(d / 32, n / 32), blk, 0, stream>>>(x, xT, n, d);

    // q = x @ Wqk^T, split precision, split-K=2 atomics into q32
    zero_f32<<<dim3(2048), blk, 0, stream>>>(q32, (size_t)n * d);
    gemm_bt_split3<2, false, true><<<dim3(d / BN, n / BM, 2), blk, 0, stream>>>(
        xhi, xlo, Whi, Wlo, q32, nullptr, nullptr, n, d, d);
    // q32 -> qhi/qlo
    split_fp32<<<dim3((n * d) / (256 * 4)), blk, 0, stream>>>(q32, qhi, qlo, (size_t)n * d);

    // S = q @ x^T, split precision, causal blocks, split-K=2 atomics into S
    zero_f32<<<dim3(4096), blk, 0, stream>>>(S, (size_t)n * n);
    gemm_bt_split3<2, true, true><<<dim3(n / BN, n / BM, 2), blk, 0, stream>>>(
        qhi, qlo, xhi, xlo, S, nullptr, nullptr, n, n, d);

    // P = causal row softmax(S), bf16, zero-padded to 128 boundary
    softmax_rows<<<dim3(n), blk, 0, stream>>>(S, P, n);

    // o = P @ x = P @ xT^T  (K limited causally per row-block), bf16
    gemm_bt<2, true, false><<<dim3(d / BN, n / BM), blk, 0, stream>>>(
        P, xT, nullptr, o, n, d, n);

    // out = o @ Wov^T, split-K=2 atomics into fp32 d_out (zeroed above)
    gemm_bt<3, false, true><<<dim3(d / BN, n / BM, 2), blk, 0, stream>>>(
        o, Wov_h, out, nullptr, n, d, d);
}

// Round 7
// 519.375 us; speedup vs baseline: 1.2638x; 1.2638x over previous
//
#include <hip/hip_runtime.h>
#include <hip/hip_bf16.h>
#include <stdint.h>
#include <stddef.h>

typedef _Float16 f16;
typedef __attribute__((ext_vector_type(8))) _Float16 f16x8;  // 4 VGPRs (MFMA A/B)
typedef __attribute__((ext_vector_type(4))) float    f32x4;  // MFMA C/D

constexpr int BM = 128, BN = 128, BK = 32;

// async global->LDS DMA, 16 B/lane; LDS dest = wave-uniform base + lane*16
#define GLOAD_LDS16(gp, lp)                                        \
    __builtin_amdgcn_global_load_lds(                              \
        (const __attribute__((address_space(1))) unsigned int*)(gp),\
        (__attribute__((address_space(3))) unsigned int*)(lp), 16, 0, 0)

// ---------------------------------------------------------------------------
// 2-term-A GEMM: C = (Ah+Al) @ B^T   (all f16, fp32 accum). 32 MFMA/barrier.
// EPI: 0 = fp32 store, 1 = f16 hi/lo split store.
// CAUSAL: skip output blocks with bx > by (square grids).
template <int EPI, bool CAUSAL>
__global__ __launch_bounds__(256) void gemm_a2(
    const f16* __restrict__ Ah, const f16* __restrict__ Al,
    const f16* __restrict__ B,
    float* __restrict__ Cf, f16* __restrict__ Co, f16* __restrict__ Clo,
    int M, int N, int K)
{
    const int bx = blockIdx.x;
    const int by = blockIdx.y;
    if (CAUSAL && bx > by) return;

    const int tid   = threadIdx.x;
    const int lane  = tid & 63;
    const int wave  = tid >> 6;
    const int wm    = wave >> 1;
    const int wn    = wave & 1;
    const int lrow  = lane & 15;
    const int lquad = lane >> 4;

    __shared__ f16 sAh[BM * BK];   // 8 KB each, 24 KB total
    __shared__ f16 sAl[BM * BK];
    __shared__ f16 sB [BN * BK];

    const int row0 = by * BM;
    const int col0 = bx * BN;

    // staging: thread t, round r covers tile row (t>>2)+64r, cols (t&3)*8..+7
    const int srow = tid >> 2;
    const int scol = (tid & 3) * 8;
    const int lbase = wave * 512;  // wave-uniform LDS element base (+r*2048)

    f32x4 acc[4][4];
    const f32x4 fzero = {0.f, 0.f, 0.f, 0.f};
    #pragma unroll
    for (int i = 0; i < 4; ++i)
        #pragma unroll
        for (int j = 0; j < 4; ++j) acc[i][j] = fzero;

    for (int k0 = 0; k0 < K; k0 += BK) {
        __syncthreads();
        #pragma unroll
        for (int r = 0; r < 2; ++r) {
            const int trow = srow + 64 * r;
            const size_t ga = (size_t)(row0 + trow) * K + k0 + scol;
            const size_t gb = (size_t)(col0 + trow) * K + k0 + scol;
            const int ldst = lbase + r * 2048;
            GLOAD_LDS16(&Ah[ga], &sAh[ldst]);
            GLOAD_LDS16(&Al[ga], &sAl[ldst]);
            GLOAD_LDS16(&B [gb], &sB [ldst]);
        }
        __syncthreads();

        f16x8 ah[4], al[4], bv[4];
        #pragma unroll
        for (int mi = 0; mi < 4; ++mi) {
            const int off = (wm * 64 + mi * 16 + lrow) * BK + lquad * 8;
            ah[mi] = *reinterpret_cast<const f16x8*>(&sAh[off]);
            al[mi] = *reinterpret_cast<const f16x8*>(&sAl[off]);
        }
        #pragma unroll
        for (int ni = 0; ni < 4; ++ni)
            bv[ni] = *reinterpret_cast<const f16x8*>(
                &sB[(wn * 64 + ni * 16 + lrow) * BK + lquad * 8]);

        #pragma unroll
        for (int mi = 0; mi < 4; ++mi)
            #pragma unroll
            for (int ni = 0; ni < 4; ++ni) {
                acc[mi][ni] = __builtin_amdgcn_mfma_f32_16x16x32_f16(
                    ah[mi], bv[ni], acc[mi][ni], 0, 0, 0);
                acc[mi][ni] = __builtin_amdgcn_mfma_f32_16x16x32_f16(
                    al[mi], bv[ni], acc[mi][ni], 0, 0, 0);
            }
    }

    // D element (row = lquad*4 + r, col = lrow) within each 16x16 tile
    #pragma unroll
    for (int mi = 0; mi < 4; ++mi) {
        #pragma unroll
        for (int ni = 0; ni < 4; ++ni) {
            #pragma unroll
            for (int r = 0; r < 4; ++r) {
                const int row = row0 + wm * 64 + mi * 16 + lquad * 4 + r;
                const int col = col0 + wn * 64 + ni * 16 + lrow;
                const size_t idx = (size_t)row * N + col;
                const float v = acc[mi][ni][r];
                if (EPI == 0) {
                    Cf[idx] = v;
                } else {
                    const f16 h = (f16)v;
                    Co[idx]  = h;
                    Clo[idx] = (f16)(v - (float)h);
                }
            }
        }
    }
}

// ---------------------------------------------------------------------------
// Plain GEMM: C = A @ B^T (f16 in, fp32 accum). 16 MFMA/barrier.
// EPI: 0 = fp32 store, 2 = f16 store.
// KCAUSAL: K limited to (by+1)*BM; by reversed so heavy blocks dispatch first.
template <int EPI, bool KCAUSAL>
__global__ __launch_bounds__(256) void gemm_plain(
    const f16* __restrict__ A, const f16* __restrict__ B,
    float* __restrict__ Cf, f16* __restrict__ Co,
    int M, int N, int K)
{
    const int bx = blockIdx.x;
    const int by = KCAUSAL ? (gridDim.y - 1 - blockIdx.y) : blockIdx.y;

    const int tid   = threadIdx.x;
    const int lane  = tid & 63;
    const int wave  = tid >> 6;
    const int wm    = wave >> 1;
    const int wn    = wave & 1;
    const int lrow  = lane & 15;
    const int lquad = lane >> 4;

    __shared__ f16 sA[BM * BK];
    __shared__ f16 sB[BN * BK];

    const int row0 = by * BM;
    const int col0 = bx * BN;

    const int srow = tid >> 2;
    const int scol = (tid & 3) * 8;
    const int lbase = wave * 512;

    f32x4 acc[4][4];
    const f32x4 fzero = {0.f, 0.f, 0.f, 0.f};
    #pragma unroll
    for (int i = 0; i < 4; ++i)
        #pragma unroll
        for (int j = 0; j < 4; ++j) acc[i][j] = fzero;

    const int Keff = KCAUSAL ? (by + 1) * BM : K;

    for (int k0 = 0; k0 < Keff; k0 += BK) {
        __syncthreads();
        #pragma unroll
        for (int r = 0; r < 2; ++r) {
            const int trow = srow + 64 * r;
            GLOAD_LDS16(&A[(size_t)(row0 + trow) * K + k0 + scol], &sA[lbase + r * 2048]);
            GLOAD_LDS16(&B[(size_t)(col0 + trow) * K + k0 + scol], &sB[lbase + r * 2048]);
        }
        __syncthreads();

        f16x8 av[4], bv[4];
        #pragma unroll
        for (int mi = 0; mi < 4; ++mi)
            av[mi] = *reinterpret_cast<const f16x8*>(
                &sA[(wm * 64 + mi * 16 + lrow) * BK + lquad * 8]);
        #pragma unroll
        for (int ni = 0; ni < 4; ++ni)
            bv[ni] = *reinterpret_cast<const f16x8*>(
                &sB[(wn * 64 + ni * 16 + lrow) * BK + lquad * 8]);

        #pragma unroll
        for (int mi = 0; mi < 4; ++mi)
            #pragma unroll
            for (int ni = 0; ni < 4; ++ni)
                acc[mi][ni] = __builtin_amdgcn_mfma_f32_16x16x32_f16(
                    av[mi], bv[ni], acc[mi][ni], 0, 0, 0);
    }

    #pragma unroll
    for (int mi = 0; mi < 4; ++mi) {
        #pragma unroll
        for (int ni = 0; ni < 4; ++ni) {
            #pragma unroll
            for (int r = 0; r < 4; ++r) {
                const int row = row0 + wm * 64 + mi * 16 + lquad * 4 + r;
                const int col = col0 + wn * 64 + ni * 16 + lrow;
                const size_t idx = (size_t)row * N + col;
                const float v = acc[mi][ni][r];
                if (EPI == 0) Cf[idx] = v;
                else          Co[idx] = (f16)v;
            }
        }
    }
}

// fp32 -> f16 hi (+ optional lo residual), 4 elems/thread
__global__ __launch_bounds__(256) void split_f32_f16(
    const float* __restrict__ in, f16* __restrict__ hi, f16* __restrict__ lo,
    size_t nelem)
{
    const size_t i = ((size_t)blockIdx.x * 256 + threadIdx.x) * 4;
    if (i >= nelem) return;
    const float4 v = *reinterpret_cast<const float4*>(in + i);
    union { f16 h[4]; ushort4 u; } H, L;
    H.h[0] = (f16)v.x; H.h[1] = (f16)v.y; H.h[2] = (f16)v.z; H.h[3] = (f16)v.w;
    *reinterpret_cast<ushort4*>(hi + i) = H.u;
    if (lo) {
        L.h[0] = (f16)(v.x - (float)H.h[0]);
        L.h[1] = (f16)(v.y - (float)H.h[1]);
        L.h[2] = (f16)(v.z - (float)H.h[2]);
        L.h[3] = (f16)(v.w - (float)H.h[3]);
        *reinterpret_cast<ushort4*>(lo + i) = L.u;
    }
}

// row-wise causal softmax, online max+sum; zero-pads P to the 128 boundary.
__global__ __launch_bounds__(256) void softmax_rows(
    const float* __restrict__ S, f16* __restrict__ P, int n)
{
    const int row = blockIdx.x;
    const int len = row + 1;
    const int padlen = ((row >> 7) + 1) << 7;
    const float* srow = S + (size_t)row * n;
    f16* prow = P + (size_t)row * n;
    const int tid = threadIdx.x;
    const int lane = tid & 63, wave = tid >> 6;
    __shared__ float redm[4], reds[4];

    float m = -3.0e38f, s = 0.f;
    for (int j = tid; j < len; j += 256) {
        const float v = srow[j];
        const float mn = fmaxf(m, v);
        s = s * __expf(m - mn) + __expf(v - mn);
        m = mn;
    }
    #pragma unroll
    for (int off = 32; off; off >>= 1) {
        const float mo = __shfl_xor(m, off, 64);
        const float so = __shfl_xor(s, off, 64);
        const float mn = fmaxf(m, mo);
        s = s * __expf(m - mn) + so * __expf(mo - mn);
        m = mn;
    }
    if (lane == 0) { redm[wave] = m; reds[wave] = s; }
    __syncthreads();
    float M = redm[0], Sm = reds[0];
    #pragma unroll
    for (int w = 1; w < 4; ++w) {
        const float mn = fmaxf(M, redm[w]);
        Sm = Sm * __expf(M - mn) + reds[w] * __expf(redm[w] - mn);
        M = mn;
    }
    const float inv = 1.0f / Sm;

    const f16 z = (f16)0.0f;
    for (int j = tid; j < padlen; j += 256)
        prow[j] = (j < len) ? (f16)(__expf(srow[j] - M) * inv) : z;
}

// out[c*rows + r] = (f16)in[r*cols + c]   (fp32 in, f16 out)
__global__ __launch_bounds__(256) void transpose_f32_f16(
    const float* __restrict__ in, f16* __restrict__ out, int rows, int cols)
{
    __shared__ float tile[32][33];
    const int bx = blockIdx.x;
    const int by = blockIdx.y;
    const int tx = threadIdx.x & 31;
    const int ty = threadIdx.x >> 5;
    #pragma unroll
    for (int r = 0; r < 4; ++r)
        tile[ty + 8 * r][tx] = in[(size_t)(by * 32 + ty + 8 * r) * cols + bx * 32 + tx];
    __syncthreads();
    #pragma unroll
    for (int r = 0; r < 4; ++r)
        out[(size_t)(bx * 32 + ty + 8 * r) * rows + by * 32 + tx] =
            (f16)tile[tx][ty + 8 * r];
}

extern "C" void kernel_launch(void* const* d_in, const int* in_sizes, int n_in,
                              void* d_out, int out_size, void* d_ws, size_t ws_size,
                              hipStream_t stream)
{
    const int n = 4096, d = 2048;
    const float* x   = (const float*)d_in[0];
    const float* Wqk = (const float*)d_in[1];
    const float* Wov = (const float*)d_in[2];
    float* out = (float*)d_out;

    char* ws = (char*)d_ws;
    const size_t MB = 1 << 20;
    f16*   xh   = (f16*)  (ws);             // 16 MB  (n x d)
    f16*   xl   = (f16*)  (ws + 16 * MB);   // 16 MB  (dead after q GEMM)
    f16*   Wh   = (f16*)  (ws + 32 * MB);   //  8 MB  (d x d, dead after q GEMM)
    f16*   Wovh = (f16*)  (ws + 40 * MB);   //  8 MB  (live to end)
    f16*   xTh  = (f16*)  (ws + 48 * MB);   // 16 MB  (d x n, live to o GEMM)
    f16*   qh   = (f16*)  (ws + 64 * MB);   // 16 MB  (dead after S GEMM)
    f16*   ql   = (f16*)  (ws + 80 * MB);   // 16 MB  (dead after S GEMM)
    float* S    = (float*)(ws + 96 * MB);   // 64 MB  (n x n)  -> peak 160 MB
    f16*   P    = (f16*)  (ws);             // 32 MB  (n x n), over xh+xl (dead)
    f16*   o    = (f16*)  (ws + 64 * MB);   // 16 MB  (n x d), over qh (dead)

    const dim3 blk(256);

    // fp32 -> f16 conversions
    split_f32_f16<<<dim3((n * d) / (256 * 4)), blk, 0, stream>>>(x,   xh, xl, (size_t)n * d);
    split_f32_f16<<<dim3((d * d) / (256 * 4)), blk, 0, stream>>>(Wqk, Wh, nullptr, (size_t)d * d);
    split_f32_f16<<<dim3((d * d) / (256 * 4)), blk, 0, stream>>>(Wov, Wovh, nullptr, (size_t)d * d);
    transpose_f32_f16<<<dim3(d / 32, n / 32), blk, 0, stream>>>(x, xTh, n, d);

    // q = (xh+xl) @ Wh^T, f16 2-term A, output split f16 hi/lo
    gemm_a2<1, false><<<dim3(d / BN, n / BM), blk, 0, stream>>>(
        xh, xl, Wh, nullptr, qh, ql, n, d, d);

    // S = (qh+ql) @ xh^T, causal blocks, fp32 store
    gemm_a2<0, true><<<dim3(n / BN, n / BM), blk, 0, stream>>>(
        qh, ql, xh, S, nullptr, nullptr, n, n, d);

    // P = causal row softmax(S), f16, zero-padded to 128 boundary
    softmax_rows<<<dim3(n), blk, 0, stream>>>(S, P, n);

    // o = P @ xTh^T  (K limited causally per row-block), f16
    gemm_plain<2, true><<<dim3(d / BN, n / BM), blk, 0, stream>>>(
        P, xTh, nullptr, o, n, d, n);

    // out = o @ Wovh^T, fp32 store to d_out
    gemm_plain<0, false><<<dim3(d / BN, n / BM), blk, 0, stream>>>(
        o, Wovh, out, nullptr, n, d, d);
}

// Round 8
// 484.584 us; speedup vs baseline: 1.3546x; 1.0718x over previous
//
#include <hip/hip_runtime.h>
#include <hip/hip_bf16.h>
#include <stdint.h>
#include <stddef.h>

typedef _Float16 f16;
typedef __attribute__((ext_vector_type(8))) _Float16 f16x8;  // 4 VGPRs (MFMA A/B)
typedef __attribute__((ext_vector_type(4))) float    f32x4;  // MFMA C/D

constexpr int BM = 128, BN = 128, BK = 64;

// async global->LDS DMA, 16 B/lane; LDS dest = wave-uniform base + lane*16
#define GLOAD_LDS16(gp, lp)                                        \
    __builtin_amdgcn_global_load_lds(                              \
        (const __attribute__((address_space(1))) unsigned int*)(gp),\
        (__attribute__((address_space(3))) unsigned int*)(lp), 16, 0, 0)

// Tile staging for BK=64: tile is 128 rows x 64 cols f16 (16 KB).
// Thread t, round r (0..3): row (t>>3)+32r, cols (t&7)*8..+7.
// LDS byte dst = t*16 + r*4096  (wave-uniform base wave*1024 + r*4096).

// ---------------------------------------------------------------------------
// 2-term-A GEMM: C = (Ah+Al) @ B^T  (f16 in, fp32 accum). 64 MFMA/barrier.
// EPI: 0 = fp32 store, 1 = f16 hi/lo split store.
// CAUSAL: skip output blocks with bx > by (square grids).
template <int EPI, bool CAUSAL>
__global__ __launch_bounds__(256) void gemm_a2(
    const f16* __restrict__ Ah, const f16* __restrict__ Al,
    const f16* __restrict__ B,
    float* __restrict__ Cf, f16* __restrict__ Co, f16* __restrict__ Clo,
    int M, int N, int K)
{
    const int bx = blockIdx.x;
    const int by = blockIdx.y;
    if (CAUSAL && bx > by) return;

    const int tid   = threadIdx.x;
    const int lane  = tid & 63;
    const int wave  = tid >> 6;
    const int wm    = wave >> 1;
    const int wn    = wave & 1;
    const int lrow  = lane & 15;
    const int lquad = lane >> 4;

    __shared__ f16 sAh[BM * BK];   // 16 KB each, 48 KB total
    __shared__ f16 sAl[BM * BK];
    __shared__ f16 sB [BN * BK];

    const int row0 = by * BM;
    const int col0 = bx * BN;

    const int srow = tid >> 3;          // 0..31
    const int scol = (tid & 7) * 8;     // 0..56
    const int lbase = wave * 512;       // elements; +r*2048 per round

    f32x4 acc[4][4];
    const f32x4 fzero = {0.f, 0.f, 0.f, 0.f};
    #pragma unroll
    for (int i = 0; i < 4; ++i)
        #pragma unroll
        for (int j = 0; j < 4; ++j) acc[i][j] = fzero;

    for (int k0 = 0; k0 < K; k0 += BK) {
        __syncthreads();
        #pragma unroll
        for (int r = 0; r < 4; ++r) {
            const int trow = srow + 32 * r;
            const size_t ga = (size_t)(row0 + trow) * K + k0 + scol;
            const size_t gb = (size_t)(col0 + trow) * K + k0 + scol;
            const int ldst = lbase + r * 2048;
            GLOAD_LDS16(&Ah[ga], &sAh[ldst]);
            GLOAD_LDS16(&Al[ga], &sAl[ldst]);
            GLOAD_LDS16(&B [gb], &sB [ldst]);
        }
        __syncthreads();

        #pragma unroll
        for (int kk = 0; kk < 2; ++kk) {
            f16x8 ah[4], al[4], bv[4];
            #pragma unroll
            for (int mi = 0; mi < 4; ++mi) {
                const int off = (wm * 64 + mi * 16 + lrow) * BK + kk * 32 + lquad * 8;
                ah[mi] = *reinterpret_cast<const f16x8*>(&sAh[off]);
                al[mi] = *reinterpret_cast<const f16x8*>(&sAl[off]);
            }
            #pragma unroll
            for (int ni = 0; ni < 4; ++ni)
                bv[ni] = *reinterpret_cast<const f16x8*>(
                    &sB[(wn * 64 + ni * 16 + lrow) * BK + kk * 32 + lquad * 8]);

            #pragma unroll
            for (int mi = 0; mi < 4; ++mi)
                #pragma unroll
                for (int ni = 0; ni < 4; ++ni) {
                    acc[mi][ni] = __builtin_amdgcn_mfma_f32_16x16x32_f16(
                        ah[mi], bv[ni], acc[mi][ni], 0, 0, 0);
                    acc[mi][ni] = __builtin_amdgcn_mfma_f32_16x16x32_f16(
                        al[mi], bv[ni], acc[mi][ni], 0, 0, 0);
                }
        }
    }

    // D element (row = lquad*4 + r, col = lrow) within each 16x16 tile
    #pragma unroll
    for (int mi = 0; mi < 4; ++mi) {
        #pragma unroll
        for (int ni = 0; ni < 4; ++ni) {
            #pragma unroll
            for (int r = 0; r < 4; ++r) {
                const int row = row0 + wm * 64 + mi * 16 + lquad * 4 + r;
                const int col = col0 + wn * 64 + ni * 16 + lrow;
                const size_t idx = (size_t)row * N + col;
                const float v = acc[mi][ni][r];
                if (EPI == 0) {
                    Cf[idx] = v;
                } else {
                    const f16 h = (f16)v;
                    Co[idx]  = h;
                    Clo[idx] = (f16)(v - (float)h);
                }
            }
        }
    }
}

// ---------------------------------------------------------------------------
// Plain GEMM: C = A @ B^T (f16 in, fp32 accum). 32 MFMA/barrier.
// EPI: 0 = fp32 store, 2 = f16 store.
// KCAUSAL: K limited to (by+1)*BM; by reversed so heavy blocks dispatch first.
template <int EPI, bool KCAUSAL>
__global__ __launch_bounds__(256) void gemm_plain(
    const f16* __restrict__ A, const f16* __restrict__ B,
    float* __restrict__ Cf, f16* __restrict__ Co,
    int M, int N, int K)
{
    const int bx = blockIdx.x;
    const int by = KCAUSAL ? (gridDim.y - 1 - blockIdx.y) : blockIdx.y;

    const int tid   = threadIdx.x;
    const int lane  = tid & 63;
    const int wave  = tid >> 6;
    const int wm    = wave >> 1;
    const int wn    = wave & 1;
    const int lrow  = lane & 15;
    const int lquad = lane >> 4;

    __shared__ f16 sA[BM * BK];   // 16 KB each, 32 KB total
    __shared__ f16 sB[BN * BK];

    const int row0 = by * BM;
    const int col0 = bx * BN;

    const int srow = tid >> 3;
    const int scol = (tid & 7) * 8;
    const int lbase = wave * 512;

    f32x4 acc[4][4];
    const f32x4 fzero = {0.f, 0.f, 0.f, 0.f};
    #pragma unroll
    for (int i = 0; i < 4; ++i)
        #pragma unroll
        for (int j = 0; j < 4; ++j) acc[i][j] = fzero;

    const int Keff = KCAUSAL ? (by + 1) * BM : K;

    for (int k0 = 0; k0 < Keff; k0 += BK) {
        __syncthreads();
        #pragma unroll
        for (int r = 0; r < 4; ++r) {
            const int trow = srow + 32 * r;
            GLOAD_LDS16(&A[(size_t)(row0 + trow) * K + k0 + scol], &sA[lbase + r * 2048]);
            GLOAD_LDS16(&B[(size_t)(col0 + trow) * K + k0 + scol], &sB[lbase + r * 2048]);
        }
        __syncthreads();

        #pragma unroll
        for (int kk = 0; kk < 2; ++kk) {
            f16x8 av[4], bv[4];
            #pragma unroll
            for (int mi = 0; mi < 4; ++mi)
                av[mi] = *reinterpret_cast<const f16x8*>(
                    &sA[(wm * 64 + mi * 16 + lrow) * BK + kk * 32 + lquad * 8]);
            #pragma unroll
            for (int ni = 0; ni < 4; ++ni)
                bv[ni] = *reinterpret_cast<const f16x8*>(
                    &sB[(wn * 64 + ni * 16 + lrow) * BK + kk * 32 + lquad * 8]);

            #pragma unroll
            for (int mi = 0; mi < 4; ++mi)
                #pragma unroll
                for (int ni = 0; ni < 4; ++ni)
                    acc[mi][ni] = __builtin_amdgcn_mfma_f32_16x16x32_f16(
                        av[mi], bv[ni], acc[mi][ni], 0, 0, 0);
        }
    }

    #pragma unroll
    for (int mi = 0; mi < 4; ++mi) {
        #pragma unroll
        for (int ni = 0; ni < 4; ++ni) {
            #pragma unroll
            for (int r = 0; r < 4; ++r) {
                const int row = row0 + wm * 64 + mi * 16 + lquad * 4 + r;
                const int col = col0 + wn * 64 + ni * 16 + lrow;
                const size_t idx = (size_t)row * N + col;
                const float v = acc[mi][ni][r];
                if (EPI == 0) Cf[idx] = v;
                else          Co[idx] = (f16)v;
            }
        }
    }
}

// fp32 -> f16 hi (+ optional lo residual), 4 elems/thread
__global__ __launch_bounds__(256) void split_f32_f16(
    const float* __restrict__ in, f16* __restrict__ hi, f16* __restrict__ lo,
    size_t nelem)
{
    const size_t i = ((size_t)blockIdx.x * 256 + threadIdx.x) * 4;
    if (i >= nelem) return;
    const float4 v = *reinterpret_cast<const float4*>(in + i);
    union { f16 h[4]; ushort4 u; } H, L;
    H.h[0] = (f16)v.x; H.h[1] = (f16)v.y; H.h[2] = (f16)v.z; H.h[3] = (f16)v.w;
    *reinterpret_cast<ushort4*>(hi + i) = H.u;
    if (lo) {
        L.h[0] = (f16)(v.x - (float)H.h[0]);
        L.h[1] = (f16)(v.y - (float)H.h[1]);
        L.h[2] = (f16)(v.z - (float)H.h[2]);
        L.h[3] = (f16)(v.w - (float)H.h[3]);
        *reinterpret_cast<ushort4*>(lo + i) = L.u;
    }
}

// row-wise causal softmax, online max+sum; zero-pads P to the 128 boundary.
__global__ __launch_bounds__(256) void softmax_rows(
    const float* __restrict__ S, f16* __restrict__ P, int n)
{
    const int row = blockIdx.x;
    const int len = row + 1;
    const int padlen = ((row >> 7) + 1) << 7;
    const float* srow = S + (size_t)row * n;
    f16* prow = P + (size_t)row * n;
    const int tid = threadIdx.x;
    const int lane = tid & 63, wave = tid >> 6;
    __shared__ float redm[4], reds[4];

    float m = -3.0e38f, s = 0.f;
    for (int j = tid; j < len; j += 256) {
        const float v = srow[j];
        const float mn = fmaxf(m, v);
        s = s * __expf(m - mn) + __expf(v - mn);
        m = mn;
    }
    #pragma unroll
    for (int off = 32; off; off >>= 1) {
        const float mo = __shfl_xor(m, off, 64);
        const float so = __shfl_xor(s, off, 64);
        const float mn = fmaxf(m, mo);
        s = s * __expf(m - mn) + so * __expf(mo - mn);
        m = mn;
    }
    if (lane == 0) { redm[wave] = m; reds[wave] = s; }
    __syncthreads();
    float M = redm[0], Sm = reds[0];
    #pragma unroll
    for (int w = 1; w < 4; ++w) {
        const float mn = fmaxf(M, redm[w]);
        Sm = Sm * __expf(M - mn) + reds[w] * __expf(redm[w] - mn);
        M = mn;
    }
    const float inv = 1.0f / Sm;

    const f16 z = (f16)0.0f;
    for (int j = tid; j < padlen; j += 256)
        prow[j] = (j < len) ? (f16)(__expf(srow[j] - M) * inv) : z;
}

// out[c*rows + r] = (f16)in[r*cols + c]   (fp32 in, f16 out)
__global__ __launch_bounds__(256) void transpose_f32_f16(
    const float* __restrict__ in, f16* __restrict__ out, int rows, int cols)
{
    __shared__ float tile[32][33];
    const int bx = blockIdx.x;
    const int by = blockIdx.y;
    const int tx = threadIdx.x & 31;
    const int ty = threadIdx.x >> 5;
    #pragma unroll
    for (int r = 0; r < 4; ++r)
        tile[ty + 8 * r][tx] = in[(size_t)(by * 32 + ty + 8 * r) * cols + bx * 32 + tx];
    __syncthreads();
    #pragma unroll
    for (int r = 0; r < 4; ++r)
        out[(size_t)(bx * 32 + ty + 8 * r) * rows + by * 32 + tx] =
            (f16)tile[tx][ty + 8 * r];
}

extern "C" void kernel_launch(void* const* d_in, const int* in_sizes, int n_in,
                              void* d_out, int out_size, void* d_ws, size_t ws_size,
                              hipStream_t stream)
{
    const int n = 4096, d = 2048;
    const float* x   = (const float*)d_in[0];
    const float* Wqk = (const float*)d_in[1];
    const float* Wov = (const float*)d_in[2];
    float* out = (float*)d_out;

    char* ws = (char*)d_ws;
    const size_t MB = 1 << 20;
    f16*   xh   = (f16*)  (ws);             // 16 MB  (n x d)
    f16*   xl   = (f16*)  (ws + 16 * MB);   // 16 MB  (dead after q GEMM)
    f16*   Wh   = (f16*)  (ws + 32 * MB);   //  8 MB  (d x d, dead after q GEMM)
    f16*   Wovh = (f16*)  (ws + 40 * MB);   //  8 MB  (live to end)
    f16*   xTh  = (f16*)  (ws + 48 * MB);   // 16 MB  (d x n, live to o GEMM)
    f16*   qh   = (f16*)  (ws + 64 * MB);   // 16 MB  (dead after S GEMM)
    f16*   ql   = (f16*)  (ws + 80 * MB);   // 16 MB  (dead after S GEMM)
    float* S    = (float*)(ws + 96 * MB);   // 64 MB  (n x n)  -> peak 160 MB
    f16*   P    = (f16*)  (ws);             // 32 MB  (n x n), over xh+xl (dead)
    f16*   o    = (f16*)  (ws + 64 * MB);   // 16 MB  (n x d), over qh (dead)

    const dim3 blk(256);

    // fp32 -> f16 conversions
    split_f32_f16<<<dim3((n * d) / (256 * 4)), blk, 0, stream>>>(x,   xh, xl, (size_t)n * d);
    split_f32_f16<<<dim3((d * d) / (256 * 4)), blk, 0, stream>>>(Wqk, Wh, nullptr, (size_t)d * d);
    split_f32_f16<<<dim3((d * d) / (256 * 4)), blk, 0, stream>>>(Wov, Wovh, nullptr, (size_t)d * d);
    transpose_f32_f16<<<dim3(d / 32, n / 32), blk, 0, stream>>>(x, xTh, n, d);

    // q = (xh+xl) @ Wh^T, f16 2-term A, output split f16 hi/lo
    gemm_a2<1, false><<<dim3(d / BN, n / BM), blk, 0, stream>>>(
        xh, xl, Wh, nullptr, qh, ql, n, d, d);

    // S = (qh+ql) @ xh^T, causal blocks, fp32 store
    gemm_a2<0, true><<<dim3(n / BN, n / BM), blk, 0, stream>>>(
        qh, ql, xh, S, nullptr, nullptr, n, n, d);

    // P = causal row softmax(S), f16, zero-padded to 128 boundary
    softmax_rows<<<dim3(n), blk, 0, stream>>>(S, P, n);

    // o = P @ xTh^T  (K limited causally per row-block), f16
    gemm_plain<2, true><<<dim3(d / BN, n / BM), blk, 0, stream>>>(
        P, xTh, nullptr, o, n, d, n);

    // out = o @ Wovh^T, fp32 store to d_out
    gemm_plain<0, false><<<dim3(d / BN, n / BM), blk, 0, stream>>>(
        o, Wovh, out, nullptr, n, d, d);
}

// Round 9
// 433.982 us; speedup vs baseline: 1.5125x; 1.1166x over previous
//
#include <hip/hip_runtime.h>
#include <hip/hip_bf16.h>
#include <stdint.h>
#include <stddef.h>

typedef _Float16 f16;
typedef __attribute__((ext_vector_type(8))) _Float16 f16x8;  // 4 VGPRs (MFMA A/B)
typedef __attribute__((ext_vector_type(4))) float    f32x4;  // MFMA C/D

constexpr int BM = 128, BN = 128, BK = 64;

// async global->LDS DMA, 16 B/lane; LDS dest = wave-uniform base + lane*16
#define GLOAD_LDS16(gp, lp)                                        \
    __builtin_amdgcn_global_load_lds(                              \
        (const __attribute__((address_space(1))) unsigned int*)(gp),\
        (__attribute__((address_space(3))) unsigned int*)(lp), 16, 0, 0)

// LDS tile 128x64 f16, XOR-swizzled: logical (row, colgrp) lives at physical
// group colgrp ^ (row & 7). DMA side: thread t (round r) writes LDS bytes
// t*16 + r*4096 (= row (t>>3)+32r, physical group t&7), so it must FETCH
// logical group (t&7)^(row&7) = (t&7)^((t>>3)&7) from global.
// Read side: fragment at (row, kk*32 + lquad*8) reads physical group
// (kk*4+lquad)^(row&7); row&7 == lrow&7 (mi*16, wm*64 are 0 mod 8).

// ---------------------------------------------------------------------------
// 2-term-A GEMM: C = (Ah+Al) @ B^T  (f16 in, fp32 accum). 64 MFMA/barrier.
// EPI: 0 = fp32 store, 1 = f16 hi/lo split store.
// CAUSAL: skip output blocks with bx > by (square grids).
template <int EPI, bool CAUSAL>
__global__ __launch_bounds__(256) void gemm_a2(
    const f16* __restrict__ Ah, const f16* __restrict__ Al,
    const f16* __restrict__ B,
    float* __restrict__ Cf, f16* __restrict__ Co, f16* __restrict__ Clo,
    int M, int N, int K)
{
    const int bx = blockIdx.x;
    const int by = blockIdx.y;
    if (CAUSAL && bx > by) return;

    const int tid   = threadIdx.x;
    const int lane  = tid & 63;
    const int wave  = tid >> 6;
    const int wm    = wave >> 1;
    const int wn    = wave & 1;
    const int lrow  = lane & 15;
    const int lquad = lane >> 4;

    __shared__ f16 sAh[BM * BK];   // 16 KB each, 48 KB total
    __shared__ f16 sAl[BM * BK];
    __shared__ f16 sB [BN * BK];

    const int row0 = by * BM;
    const int col0 = bx * BN;

    const int srow = tid >> 3;                               // 0..31
    const int scol = (((tid & 7) ^ ((tid >> 3) & 7))) * 8;   // swizzled source col
    const int lbase = wave * 512;                            // +r*2048 per round

    f32x4 acc[4][4];
    const f32x4 fzero = {0.f, 0.f, 0.f, 0.f};
    #pragma unroll
    for (int i = 0; i < 4; ++i)
        #pragma unroll
        for (int j = 0; j < 4; ++j) acc[i][j] = fzero;

    for (int k0 = 0; k0 < K; k0 += BK) {
        __syncthreads();
        #pragma unroll
        for (int r = 0; r < 4; ++r) {
            const int trow = srow + 32 * r;
            const size_t ga = (size_t)(row0 + trow) * K + k0 + scol;
            const size_t gb = (size_t)(col0 + trow) * K + k0 + scol;
            const int ldst = lbase + r * 2048;
            GLOAD_LDS16(&Ah[ga], &sAh[ldst]);
            GLOAD_LDS16(&Al[ga], &sAl[ldst]);
            GLOAD_LDS16(&B [gb], &sB [ldst]);
        }
        __syncthreads();

        #pragma unroll
        for (int kk = 0; kk < 2; ++kk) {
            const int grpA = ((kk * 4 + lquad) ^ (lrow & 7)) * 8;
            f16x8 ah[4], al[4], bv[4];
            #pragma unroll
            for (int mi = 0; mi < 4; ++mi) {
                const int off = (wm * 64 + mi * 16 + lrow) * BK + grpA;
                ah[mi] = *reinterpret_cast<const f16x8*>(&sAh[off]);
                al[mi] = *reinterpret_cast<const f16x8*>(&sAl[off]);
            }
            #pragma unroll
            for (int ni = 0; ni < 4; ++ni)
                bv[ni] = *reinterpret_cast<const f16x8*>(
                    &sB[(wn * 64 + ni * 16 + lrow) * BK + grpA]);

            #pragma unroll
            for (int mi = 0; mi < 4; ++mi)
                #pragma unroll
                for (int ni = 0; ni < 4; ++ni) {
                    acc[mi][ni] = __builtin_amdgcn_mfma_f32_16x16x32_f16(
                        ah[mi], bv[ni], acc[mi][ni], 0, 0, 0);
                    acc[mi][ni] = __builtin_amdgcn_mfma_f32_16x16x32_f16(
                        al[mi], bv[ni], acc[mi][ni], 0, 0, 0);
                }
        }
    }

    // D element (row = lquad*4 + r, col = lrow) within each 16x16 tile
    #pragma unroll
    for (int mi = 0; mi < 4; ++mi) {
        #pragma unroll
        for (int ni = 0; ni < 4; ++ni) {
            #pragma unroll
            for (int r = 0; r < 4; ++r) {
                const int row = row0 + wm * 64 + mi * 16 + lquad * 4 + r;
                const int col = col0 + wn * 64 + ni * 16 + lrow;
                const size_t idx = (size_t)row * N + col;
                const float v = acc[mi][ni][r];
                if (EPI == 0) {
                    Cf[idx] = v;
                } else {
                    const f16 h = (f16)v;
                    Co[idx]  = h;
                    Clo[idx] = (f16)(v - (float)h);
                }
            }
        }
    }
}

// ---------------------------------------------------------------------------
// Plain GEMM: C = A @ B^T (f16 in, fp32 accum). 32 MFMA/barrier.
// EPI: 0 = fp32 store, 2 = f16 store.
// KCAUSAL: K limited to (by+1)*BM; by reversed so heavy blocks dispatch first.
template <int EPI, bool KCAUSAL>
__global__ __launch_bounds__(256) void gemm_plain(
    const f16* __restrict__ A, const f16* __restrict__ B,
    float* __restrict__ Cf, f16* __restrict__ Co,
    int M, int N, int K)
{
    const int bx = blockIdx.x;
    const int by = KCAUSAL ? (gridDim.y - 1 - blockIdx.y) : blockIdx.y;

    const int tid   = threadIdx.x;
    const int lane  = tid & 63;
    const int wave  = tid >> 6;
    const int wm    = wave >> 1;
    const int wn    = wave & 1;
    const int lrow  = lane & 15;
    const int lquad = lane >> 4;

    __shared__ f16 sA[BM * BK];   // 16 KB each, 32 KB total
    __shared__ f16 sB[BN * BK];

    const int row0 = by * BM;
    const int col0 = bx * BN;

    const int srow = tid >> 3;
    const int scol = (((tid & 7) ^ ((tid >> 3) & 7))) * 8;
    const int lbase = wave * 512;

    f32x4 acc[4][4];
    const f32x4 fzero = {0.f, 0.f, 0.f, 0.f};
    #pragma unroll
    for (int i = 0; i < 4; ++i)
        #pragma unroll
        for (int j = 0; j < 4; ++j) acc[i][j] = fzero;

    const int Keff = KCAUSAL ? (by + 1) * BM : K;

    for (int k0 = 0; k0 < Keff; k0 += BK) {
        __syncthreads();
        #pragma unroll
        for (int r = 0; r < 4; ++r) {
            const int trow = srow + 32 * r;
            GLOAD_LDS16(&A[(size_t)(row0 + trow) * K + k0 + scol], &sA[lbase + r * 2048]);
            GLOAD_LDS16(&B[(size_t)(col0 + trow) * K + k0 + scol], &sB[lbase + r * 2048]);
        }
        __syncthreads();

        #pragma unroll
        for (int kk = 0; kk < 2; ++kk) {
            const int grpA = ((kk * 4 + lquad) ^ (lrow & 7)) * 8;
            f16x8 av[4], bv[4];
            #pragma unroll
            for (int mi = 0; mi < 4; ++mi)
                av[mi] = *reinterpret_cast<const f16x8*>(
                    &sA[(wm * 64 + mi * 16 + lrow) * BK + grpA]);
            #pragma unroll
            for (int ni = 0; ni < 4; ++ni)
                bv[ni] = *reinterpret_cast<const f16x8*>(
                    &sB[(wn * 64 + ni * 16 + lrow) * BK + grpA]);

            #pragma unroll
            for (int mi = 0; mi < 4; ++mi)
                #pragma unroll
                for (int ni = 0; ni < 4; ++ni)
                    acc[mi][ni] = __builtin_amdgcn_mfma_f32_16x16x32_f16(
                        av[mi], bv[ni], acc[mi][ni], 0, 0, 0);
        }
    }

    #pragma unroll
    for (int mi = 0; mi < 4; ++mi) {
        #pragma unroll
        for (int ni = 0; ni < 4; ++ni) {
            #pragma unroll
            for (int r = 0; r < 4; ++r) {
                const int row = row0 + wm * 64 + mi * 16 + lquad * 4 + r;
                const int col = col0 + wn * 64 + ni * 16 + lrow;
                const size_t idx = (size_t)row * N + col;
                const float v = acc[mi][ni][r];
                if (EPI == 0) Cf[idx] = v;
                else          Co[idx] = (f16)v;
            }
        }
    }
}

// fp32 -> f16 hi (+ optional lo residual), 4 elems/thread
__global__ __launch_bounds__(256) void split_f32_f16(
    const float* __restrict__ in, f16* __restrict__ hi, f16* __restrict__ lo,
    size_t nelem)
{
    const size_t i = ((size_t)blockIdx.x * 256 + threadIdx.x) * 4;
    if (i >= nelem) return;
    const float4 v = *reinterpret_cast<const float4*>(in + i);
    union { f16 h[4]; ushort4 u; } H, L;
    H.h[0] = (f16)v.x; H.h[1] = (f16)v.y; H.h[2] = (f16)v.z; H.h[3] = (f16)v.w;
    *reinterpret_cast<ushort4*>(hi + i) = H.u;
    if (lo) {
        L.h[0] = (f16)(v.x - (float)H.h[0]);
        L.h[1] = (f16)(v.y - (float)H.h[1]);
        L.h[2] = (f16)(v.z - (float)H.h[2]);
        L.h[3] = (f16)(v.w - (float)H.h[3]);
        *reinterpret_cast<ushort4*>(lo + i) = L.u;
    }
}

// row-wise causal softmax, online max+sum; zero-pads P to the 128 boundary.
__global__ __launch_bounds__(256) void softmax_rows(
    const float* __restrict__ S, f16* __restrict__ P, int n)
{
    const int row = blockIdx.x;
    const int len = row + 1;
    const int padlen = ((row >> 7) + 1) << 7;
    const float* srow = S + (size_t)row * n;
    f16* prow = P + (size_t)row * n;
    const int tid = threadIdx.x;
    const int lane = tid & 63, wave = tid >> 6;
    __shared__ float redm[4], reds[4];

    float m = -3.0e38f, s = 0.f;
    for (int j = tid; j < len; j += 256) {
        const float v = srow[j];
        const float mn = fmaxf(m, v);
        s = s * __expf(m - mn) + __expf(v - mn);
        m = mn;
    }
    #pragma unroll
    for (int off = 32; off; off >>= 1) {
        const float mo = __shfl_xor(m, off, 64);
        const float so = __shfl_xor(s, off, 64);
        const float mn = fmaxf(m, mo);
        s = s * __expf(m - mn) + so * __expf(mo - mn);
        m = mn;
    }
    if (lane == 0) { redm[wave] = m; reds[wave] = s; }
    __syncthreads();
    float M = redm[0], Sm = reds[0];
    #pragma unroll
    for (int w = 1; w < 4; ++w) {
        const float mn = fmaxf(M, redm[w]);
        Sm = Sm * __expf(M - mn) + reds[w] * __expf(redm[w] - mn);
        M = mn;
    }
    const float inv = 1.0f / Sm;

    const f16 z = (f16)0.0f;
    for (int j = tid; j < padlen; j += 256)
        prow[j] = (j < len) ? (f16)(__expf(srow[j] - M) * inv) : z;
}

// out[c*rows + r] = (f16)in[r*cols + c]   (fp32 in, f16 out)
__global__ __launch_bounds__(256) void transpose_f32_f16(
    const float* __restrict__ in, f16* __restrict__ out, int rows, int cols)
{
    __shared__ float tile[32][33];
    const int bx = blockIdx.x;
    const int by = blockIdx.y;
    const int tx = threadIdx.x & 31;
    const int ty = threadIdx.x >> 5;
    #pragma unroll
    for (int r = 0; r < 4; ++r)
        tile[ty + 8 * r][tx] = in[(size_t)(by * 32 + ty + 8 * r) * cols + bx * 32 + tx];
    __syncthreads();
    #pragma unroll
    for (int r = 0; r < 4; ++r)
        out[(size_t)(bx * 32 + ty + 8 * r) * rows + by * 32 + tx] =
            (f16)tile[tx][ty + 8 * r];
}

extern "C" void kernel_launch(void* const* d_in, const int* in_sizes, int n_in,
                              void* d_out, int out_size, void* d_ws, size_t ws_size,
                              hipStream_t stream)
{
    const int n = 4096, d = 2048;
    const float* x   = (const float*)d_in[0];
    const float* Wqk = (const float*)d_in[1];
    const float* Wov = (const float*)d_in[2];
    float* out = (float*)d_out;

    char* ws = (char*)d_ws;
    const size_t MB = 1 << 20;
    f16*   xh   = (f16*)  (ws);             // 16 MB  (n x d)
    f16*   xl   = (f16*)  (ws + 16 * MB);   // 16 MB  (dead after q GEMM)
    f16*   Wh   = (f16*)  (ws + 32 * MB);   //  8 MB  (d x d, dead after q GEMM)
    f16*   Wovh = (f16*)  (ws + 40 * MB);   //  8 MB  (live to end)
    f16*   xTh  = (f16*)  (ws + 48 * MB);   // 16 MB  (d x n, live to o GEMM)
    f16*   qh   = (f16*)  (ws + 64 * MB);   // 16 MB  (dead after S GEMM)
    f16*   ql   = (f16*)  (ws + 80 * MB);   // 16 MB  (dead after S GEMM)
    float* S    = (float*)(ws + 96 * MB);   // 64 MB  (n x n)  -> peak 160 MB
    f16*   P    = (f16*)  (ws);             // 32 MB  (n x n), over xh+xl (dead)
    f16*   o    = (f16*)  (ws + 64 * MB);   // 16 MB  (n x d), over qh (dead)

    const dim3 blk(256);

    // fp32 -> f16 conversions
    split_f32_f16<<<dim3((n * d) / (256 * 4)), blk, 0, stream>>>(x,   xh, xl, (size_t)n * d);
    split_f32_f16<<<dim3((d * d) / (256 * 4)), blk, 0, stream>>>(Wqk, Wh, nullptr, (size_t)d * d);
    split_f32_f16<<<dim3((d * d) / (256 * 4)), blk, 0, stream>>>(Wov, Wovh, nullptr, (size_t)d * d);
    transpose_f32_f16<<<dim3(d / 32, n / 32), blk, 0, stream>>>(x, xTh, n, d);

    // q = (xh+xl) @ Wh^T, f16 2-term A, output split f16 hi/lo
    gemm_a2<1, false><<<dim3(d / BN, n / BM), blk, 0, stream>>>(
        xh, xl, Wh, nullptr, qh, ql, n, d, d);

    // S = (qh+ql) @ xh^T, causal blocks, fp32 store
    gemm_a2<0, true><<<dim3(n / BN, n / BM), blk, 0, stream>>>(
        qh, ql, xh, S, nullptr, nullptr, n, n, d);

    // P = causal row softmax(S), f16, zero-padded to 128 boundary
    softmax_rows<<<dim3(n), blk, 0, stream>>>(S, P, n);

    // o = P @ xTh^T  (K limited causally per row-block), f16
    gemm_plain<2, true><<<dim3(d / BN, n / BM), blk, 0, stream>>>(
        P, xTh, nullptr, o, n, d, n);

    // out = o @ Wovh^T, fp32 store to d_out
    gemm_plain<0, false><<<dim3(d / BN, n / BM), blk, 0, stream>>>(
        o, Wovh, out, nullptr, n, d, d);
}